// Round 17
// baseline (222.710 us; speedup 1.0000x reference)
//
#include <hip/hip_runtime.h>
#include <hip/hip_fp16.h>
#include <math.h>

// MaxSim contrastive loss, MI355X.
// Round-17 = round-16 occupancy plan with the staging-coverage bug fixed.
// r16 NaN cause: A staged 1 float4/thread = half the 128x32 tile written.
// Fix: A uses r15's verified map (8 floats/thread, f16x8 write, full cover);
// B staged by ALL 512 threads at 4 floats each (64x32 = exactly 512 float4),
// float2 half-slot writes. acc[2][2]=16 regs + staged 12 -> targets <=64
// total regs for __launch_bounds__(512,8): 8 waves/SIMD, 4 blocks/CU (24KB).

constexpr int NB = 128;
constexpr int LQ = 256;
constexpr int LK = 512;
constexpr int DD = 1024;

#define TEMP_INV 20.0f
#define EPSN 1e-12f

typedef __fp16 fp16x2 __attribute__((ext_vector_type(2)));   // cvt_pkrtz return
typedef _Float16 f16x8 __attribute__((ext_vector_type(8)));  // MFMA operand
typedef float f32x4 __attribute__((ext_vector_type(4)));

#define BM 128
#define BN 64
#define BK 32
#define KITERS 32   // DD/BK

__device__ inline f16x8 cvt8(float4 a, float4 b) {
  union { f16x8 v; fp16x2 h[4]; } u;
  u.h[0] = __builtin_amdgcn_cvt_pkrtz(a.x, a.y);
  u.h[1] = __builtin_amdgcn_cvt_pkrtz(a.z, a.w);
  u.h[2] = __builtin_amdgcn_cvt_pkrtz(b.x, b.y);
  u.h[3] = __builtin_amdgcn_cvt_pkrtz(b.z, b.w);
  return u.v;
}

// merged-row f16 LDS index (r15-verified): two BK=32 rows per 128B line.
__device__ __forceinline__ int lidxR(int row, int kg) {
  const int line = row >> 1;
  const int slot = (kg | ((row & 1) << 2)) ^ (line & 7);
  return line * 64 + slot * 8;
}

__global__ __launch_bounds__(512, 8) void maxsim_kernel(
    const float* __restrict__ q, const float* __restrict__ pk,
    const float* __restrict__ nk, const int* __restrict__ pmask,
    const int* __restrict__ nmask, float* __restrict__ part) {
  __shared__ _Float16 __align__(16) As[2][BM * BK];  // 2 x 8 KB
  __shared__ _Float16 __align__(16) Bs[2][BN * BK];  // 2 x 4 KB  (24 KB)

  // XCD-aware bijective swizzle: 4096 blocks = 8 XCDs x 512
  const int bid = blockIdx.x;
  const int sw = (bid & 7) * 512 + (bid >> 3);
  const int b = sw >> 5;         // batch (32 blocks/batch)
  const int x = sw & 31;
  const int mt = x >> 4;         // 0..1  (q tile, 128 rows)
  const int nt = (x >> 1) & 7;   // 0..7  (key tile, 64 rows)
  const int kt = x & 1;          // 0=pos 1=neg

  const float* kbase = kt ? nk : pk;
  const int* mbase = kt ? nmask : pmask;

  const float* Ag = q + ((size_t)b * LQ + mt * BM) * DD;
  const float* Bg = kbase + ((size_t)b * LK + nt * BN) * DD;

  const int tid = threadIdx.x;
  const int lane = tid & 63;
  const int w = tid >> 6;        // 0..7
  const int wr = w >> 1;         // 0..3 : A rows wr*32 + [0,32)
  const int wc = w & 1;          // 0..1 : B rows wc*32 + [0,32)
  const int frow = lane & 15;
  const int kgrp = lane >> 4;    // 0..3

  // A staging (r15-verified): thread t -> row t>>2 (0..127), 8-col chunk t&3
  const int rA = tid >> 2;
  const int cA = tid & 3;
  const float* pA = Ag + (size_t)rA * DD + cA * 8;
  const int wAo = lidxR(rA, cA);
  // B staging: thread t -> row t>>3 (0..63), float4 sub-chunk t&7
  const int rB = tid >> 3;
  const int sB = tid & 7;
  const float* pB = Bg + (size_t)rB * DD + sB * 4;
  const int wBo = lidxR(rB, sB >> 1) + (sB & 1) * 4;

  float ssqA = 0.f, ssqB = 0.f;
  f32x4 acc[2][2] = {};

  auto LOADS = [&](int it, float4& a0, float4& a1, float4& bv) {
    const int koff = it * BK;    // compile-time after unroll -> imm offsets
    a0 = *(const float4*)(pA + koff);
    a1 = *(const float4*)(pA + koff + 4);
    bv = *(const float4*)(pB + koff);
  };
  auto STORE = [&](int bsel, float4 a0, float4 a1, float4 bv) {
    ssqA += a0.x * a0.x + a0.y * a0.y + a0.z * a0.z + a0.w * a0.w +
            a1.x * a1.x + a1.y * a1.y + a1.z * a1.z + a1.w * a1.w;
    ssqB += bv.x * bv.x + bv.y * bv.y + bv.z * bv.z + bv.w * bv.w;
    *(f16x8*)&As[bsel][wAo] = cvt8(a0, a1);
    union { fp16x2 h[2]; float2 f; } ub;
    ub.h[0] = __builtin_amdgcn_cvt_pkrtz(bv.x, bv.y);
    ub.h[1] = __builtin_amdgcn_cvt_pkrtz(bv.z, bv.w);
    *(float2*)&Bs[bsel][wBo] = ub.f;
  };
  auto COMPUTE = [&](int bsel) {
    __builtin_amdgcn_s_setprio(1);
    f16x8 af[2], bf[2];
    #pragma unroll
    for (int m = 0; m < 2; ++m)
      af[m] = *(const f16x8*)&As[bsel][lidxR(wr * 32 + m * 16 + frow, kgrp)];
    #pragma unroll
    for (int n = 0; n < 2; ++n)
      bf[n] = *(const f16x8*)&Bs[bsel][lidxR(wc * 32 + n * 16 + frow, kgrp)];
    #pragma unroll
    for (int m = 0; m < 2; ++m)
      #pragma unroll
      for (int n = 0; n < 2; ++n)
        acc[m][n] = __builtin_amdgcn_mfma_f32_16x16x32_f16(af[m], bf[n], acc[m][n], 0, 0, 0);
    __builtin_amdgcn_s_setprio(0);
  };

  {
    float4 a0, a1, bv;
    LOADS(0, a0, a1, bv);
    STORE(0, a0, a1, bv);
  }
  __syncthreads();

  #pragma unroll
  for (int it = 0; it < KITERS - 1; ++it) {
    float4 a0, a1, bv;
    LOADS(it + 1, a0, a1, bv);   // imm-offset loads, issue early
    __builtin_amdgcn_sched_barrier(0);
    COMPUTE(it & 1);
    STORE((it & 1) ^ 1, a0, a1, bv);
    __syncthreads();
  }
  COMPUTE(1);                // tile 31 (buf 1)

  // ---- epilogue: norms, column scales, row-max ----
  // ssqA: reduce over the 4 A-chunk lanes (bits 0-1); ssqB over 8 sub-lanes
  ssqA += __shfl_xor(ssqA, 1); ssqA += __shfl_xor(ssqA, 2);
  ssqB += __shfl_xor(ssqB, 1); ssqB += __shfl_xor(ssqB, 2);
  ssqB += __shfl_xor(ssqB, 4);

  // aux aliased onto As[0]; final COMPUTE read As[1]/Bs[1] only; last As[0]
  // read (COMPUTE(0) at it=30) is barrier-separated from these writes.
  float* const aux = reinterpret_cast<float*>(&As[0][0]);
  float* const csc = aux;             // [BN=64]  (1/|k|)*mask
  float* const invA_s = aux + BN;     // [BM=128] 1/|q|
  float* const rmax = aux + BN + BM;  // [BM][2]

  if (cA == 0) invA_s[rA] = 1.0f / fmaxf(sqrtf(ssqA), EPSN);
  if (sB == 0) {
    const int key = nt * BN + rB;
    csc[rB] = (mbase[(size_t)b * LK + key] ? 1.0f : 0.0f) /
              fmaxf(sqrtf(ssqB), EPSN);
  }
  __syncthreads();

  float vm4[2][4];
  #pragma unroll
  for (int m = 0; m < 2; ++m)
    #pragma unroll
    for (int r = 0; r < 4; ++r) vm4[m][r] = -INFINITY;
  #pragma unroll
  for (int n = 0; n < 2; ++n) {
    const float s = csc[wc * 32 + n * 16 + frow];
    #pragma unroll
    for (int m = 0; m < 2; ++m)
      #pragma unroll
      for (int r = 0; r < 4; ++r)
        vm4[m][r] = fmaxf(vm4[m][r], acc[m][n][r] * s);
  }
  #pragma unroll
  for (int off = 1; off < 16; off <<= 1)
    #pragma unroll
    for (int m = 0; m < 2; ++m)
      #pragma unroll
      for (int r = 0; r < 4; ++r)
        vm4[m][r] = fmaxf(vm4[m][r], __shfl_xor(vm4[m][r], off));
  if ((lane & 15) == 0) {
    #pragma unroll
    for (int m = 0; m < 2; ++m)
      #pragma unroll
      for (int r = 0; r < 4; ++r)
        rmax[(wr * 32 + m * 16 + kgrp * 4 + r) * 2 + wc] = vm4[m][r];
  }
  __syncthreads();
  if (tid < BM) {
    const float v = fmaxf(rmax[tid * 2], rmax[tid * 2 + 1]) * invA_s[tid];
    part[(((size_t)kt * NB + b) * 8 + nt) * LQ + mt * BM + tid] = v;
  }
}

// ---------------- logits + softplus per batch (r13-verified, 8 ntiles) ----
__global__ __launch_bounds__(256) void logits_kernel(
    const float* __restrict__ part, const int* __restrict__ qmask,
    float* __restrict__ nll) {
  int b = blockIdx.x;
  int t = threadIdx.x;  // = lq
  float mp = -INFINITY, mn = -INFINITY;
  #pragma unroll
  for (int ntile = 0; ntile < 8; ++ntile) {
    mp = fmaxf(mp, part[(((size_t)0 * NB + b) * 8 + ntile) * LQ + t]);
    mn = fmaxf(mn, part[(((size_t)1 * NB + b) * 8 + ntile) * LQ + t]);
  }
  float qm = qmask[(size_t)b * LQ + t] ? 1.0f : 0.0f;
  float p = mp * qm;  // 1/|q| already folded into part
  float n = mn * qm;
  #pragma unroll
  for (int o = 32; o; o >>= 1) { p += __shfl_down(p, o); n += __shfl_down(n, o); }
  __shared__ float sp[4], sn[4];
  int lane = t & 63, w = t >> 6;
  if (lane == 0) { sp[w] = p; sn[w] = n; }
  __syncthreads();
  if (t == 0) {
    float ps = sp[0] + sp[1] + sp[2] + sp[3];
    float ns = sn[0] + sn[1] + sn[2] + sn[3];
    float z = (ns - ps) * TEMP_INV;
    nll[b] = z > 0.0f ? z + log1pf(expf(-z)) : log1pf(expf(z));
  }
}

__global__ void finalize_kernel(const float* __restrict__ nll, float* __restrict__ out) {
  __shared__ float s[128];
  int t = threadIdx.x;
  s[t] = nll[t];
  __syncthreads();
  #pragma unroll
  for (int o = 64; o; o >>= 1) {
    if (t < o) s[t] += s[t + o];
    __syncthreads();
  }
  if (t == 0) out[0] = s[0] * (1.0f / 128.0f);
}

extern "C" void kernel_launch(void* const* d_in, const int* in_sizes, int n_in,
                              void* d_out, int out_size, void* d_ws, size_t ws_size,
                              hipStream_t stream) {
  const float* q = (const float*)d_in[0];
  const float* pk = (const float*)d_in[1];
  const float* nk = (const float*)d_in[2];
  const int* qm = (const int*)d_in[3];
  const int* pm = (const int*)d_in[4];
  const int* nm = (const int*)d_in[5];

  float* ws = (float*)d_ws;
  float* part = ws;                // 524288 floats: [kt][b][nt(8)][lq]
  float* nll = part + 524288;      // 128 floats

  maxsim_kernel<<<4096, 512, 0, stream>>>(q, pk, nk, pm, nm, part);
  logits_kernel<<<NB, 256, 0, stream>>>(part, qm, nll);
  finalize_kernel<<<1, 128, 0, stream>>>(nll, (float*)d_out);
}

// Round 18
// 186.257 us; speedup vs baseline: 1.1957x; 1.1957x over previous
//
#include <hip/hip_runtime.h>
#include <hip/hip_fp16.h>
#include <math.h>

// MaxSim contrastive loss, MI355X.
// Round-18: pos/neg fusion. Cross-round data says dur tracks sequential
// phase-slots with ~constant per-slot cost; occupancy (r17: 86%, slower) and
// VALU (r14) are not binding. One block now computes BOTH pos and neg key
// tiles against a SHARED staged q tile: same 64 phase-slots as the champion
// but 25% less staging per slot (A staged once per 2x MFMA work), half the
// blocks, half the q global traffic. Components all verified: r15 staging
// map + merged-row lidxR LDS layout (0 conflicts) x3 tiles, r14 4-ntile
// part/logits, XCD-bijective swizzle (1024 = 8 x 128).

constexpr int NB = 128;
constexpr int LQ = 256;
constexpr int LK = 512;
constexpr int DD = 1024;

#define TEMP_INV 20.0f
#define EPSN 1e-12f

typedef __fp16 fp16x2 __attribute__((ext_vector_type(2)));   // cvt_pkrtz return
typedef _Float16 f16x8 __attribute__((ext_vector_type(8)));  // MFMA operand
typedef float f32x4 __attribute__((ext_vector_type(4)));

#define BM 128
#define BN 128
#define BK 32
#define KITERS 32   // DD/BK

__device__ inline f16x8 cvt8(float4 a, float4 b) {
  union { f16x8 v; fp16x2 h[4]; } u;
  u.h[0] = __builtin_amdgcn_cvt_pkrtz(a.x, a.y);
  u.h[1] = __builtin_amdgcn_cvt_pkrtz(a.z, a.w);
  u.h[2] = __builtin_amdgcn_cvt_pkrtz(b.x, b.y);
  u.h[3] = __builtin_amdgcn_cvt_pkrtz(b.z, b.w);
  return u.v;
}

// merged-row f16 LDS index (r15-verified): two BK=32 rows per 128B line.
__device__ __forceinline__ int lidxR(int row, int kg) {
  const int line = row >> 1;
  const int slot = (kg | ((row & 1) << 2)) ^ (line & 7);
  return line * 64 + slot * 8;
}

__global__ __launch_bounds__(512, 4) void maxsim_kernel(
    const float* __restrict__ q, const float* __restrict__ pk,
    const float* __restrict__ nk, const int* __restrict__ pmask,
    const int* __restrict__ nmask, float* __restrict__ part) {
  __shared__ _Float16 __align__(16) As[2][BM * BK];   // 16 KB
  __shared__ _Float16 __align__(16) Bps[2][BN * BK];  // 16 KB
  __shared__ _Float16 __align__(16) Bns[2][BN * BK];  // 16 KB  (48 KB)

  // XCD-aware bijective swizzle: 1024 blocks = 8 XCDs x 128
  const int bid = blockIdx.x;
  const int sw = (bid & 7) * 128 + (bid >> 3);
  const int b = sw >> 3;         // batch (8 blocks/batch)
  const int x = sw & 7;
  const int mt = x >> 2;         // 0..1  (q tile)
  const int nt = x & 3;          // 0..3  (key tile, both pos & neg)

  const float* Ag = q + ((size_t)b * LQ + mt * BM) * DD;
  const float* Pg = pk + ((size_t)b * LK + nt * BN) * DD;
  const float* Ng = nk + ((size_t)b * LK + nt * BN) * DD;

  const int tid = threadIdx.x;
  const int lane = tid & 63;
  const int w = tid >> 6;        // 0..7
  const int wr = w >> 1;         // 0..3 : A rows wr*32 + [0,32)
  const int wc = w & 1;          // 0..1 : B rows wc*64 + [0,64)
  const int frow = lane & 15;
  const int kgrp = lane >> 4;    // 0..3

  // staging (r15-verified map): thread t -> row t>>2 (0..127), 8-col chunk t&3
  const int rowS = tid >> 2;
  const int chS = tid & 3;
  const float* pA = Ag + (size_t)rowS * DD + chS * 8;
  const float* pP = Pg + (size_t)rowS * DD + chS * 8;
  const float* pN = Ng + (size_t)rowS * DD + chS * 8;
  const int sidx = lidxR(rowS, chS);

  float ssqA = 0.f, ssqP = 0.f, ssqN = 0.f;
  f32x4 accp[2][4] = {};
  f32x4 accn[2][4] = {};

  auto LOADS = [&](int it, float4& a0, float4& a1, float4& p0, float4& p1,
                   float4& n0, float4& n1) {
    const int koff = it * BK;    // compile-time after unroll -> imm offsets
    a0 = *(const float4*)(pA + koff);
    a1 = *(const float4*)(pA + koff + 4);
    p0 = *(const float4*)(pP + koff);
    p1 = *(const float4*)(pP + koff + 4);
    n0 = *(const float4*)(pN + koff);
    n1 = *(const float4*)(pN + koff + 4);
  };
  auto STORE = [&](int bsel, float4 a0, float4 a1, float4 p0, float4 p1,
                   float4 n0, float4 n1) {
    ssqA += a0.x * a0.x + a0.y * a0.y + a0.z * a0.z + a0.w * a0.w +
            a1.x * a1.x + a1.y * a1.y + a1.z * a1.z + a1.w * a1.w;
    ssqP += p0.x * p0.x + p0.y * p0.y + p0.z * p0.z + p0.w * p0.w +
            p1.x * p1.x + p1.y * p1.y + p1.z * p1.z + p1.w * p1.w;
    ssqN += n0.x * n0.x + n0.y * n0.y + n0.z * n0.z + n0.w * n0.w +
            n1.x * n1.x + n1.y * n1.y + n1.z * n1.z + n1.w * n1.w;
    *(f16x8*)&As[bsel][sidx] = cvt8(a0, a1);
    *(f16x8*)&Bps[bsel][sidx] = cvt8(p0, p1);
    *(f16x8*)&Bns[bsel][sidx] = cvt8(n0, n1);
  };
  auto COMPUTE = [&](int bsel) {
    __builtin_amdgcn_s_setprio(1);
    f16x8 af[2];
    #pragma unroll
    for (int m = 0; m < 2; ++m)
      af[m] = *(const f16x8*)&As[bsel][lidxR(wr * 32 + m * 16 + frow, kgrp)];
    #pragma unroll
    for (int n = 0; n < 4; ++n) {
      const int ro = lidxR(wc * 64 + n * 16 + frow, kgrp);
      f16x8 bp = *(const f16x8*)&Bps[bsel][ro];
      f16x8 bn = *(const f16x8*)&Bns[bsel][ro];
      #pragma unroll
      for (int m = 0; m < 2; ++m) {
        accp[m][n] = __builtin_amdgcn_mfma_f32_16x16x32_f16(af[m], bp, accp[m][n], 0, 0, 0);
        accn[m][n] = __builtin_amdgcn_mfma_f32_16x16x32_f16(af[m], bn, accn[m][n], 0, 0, 0);
      }
    }
    __builtin_amdgcn_s_setprio(0);
  };

  {
    float4 a0, a1, p0, p1, n0, n1;
    LOADS(0, a0, a1, p0, p1, n0, n1);
    STORE(0, a0, a1, p0, p1, n0, n1);
  }
  __syncthreads();

  #pragma unroll
  for (int it = 0; it < KITERS - 1; ++it) {
    float4 a0, a1, p0, p1, n0, n1;
    LOADS(it + 1, a0, a1, p0, p1, n0, n1);  // imm-offset loads, issue early
    __builtin_amdgcn_sched_barrier(0);
    COMPUTE(it & 1);
    STORE((it & 1) ^ 1, a0, a1, p0, p1, n0, n1);
    __syncthreads();
  }
  COMPUTE(1);                // tile 31 (buf 1)

  // ---- epilogue: norms, column scales, row-max (components r12/r15) ----
  ssqA += __shfl_xor(ssqA, 1); ssqA += __shfl_xor(ssqA, 2);
  ssqP += __shfl_xor(ssqP, 1); ssqP += __shfl_xor(ssqP, 2);
  ssqN += __shfl_xor(ssqN, 1); ssqN += __shfl_xor(ssqN, 2);

  // aux aliased onto As[0] (2048 floats; need 896). Last As[0]/Bps[0]/Bns[0]
  // reads were COMPUTE(0) at it=30, barrier-separated from these writes.
  float* const aux = reinterpret_cast<float*>(&As[0][0]);
  float* const invA_s = aux;            // [128]
  float* const cscP = aux + 128;        // [128]
  float* const cscN = aux + 256;        // [128]
  float* const rmaxP = aux + 384;       // [128][2]
  float* const rmaxN = aux + 640;       // [128][2]

  if (chS == 0) {
    invA_s[rowS] = 1.0f / fmaxf(sqrtf(ssqA), EPSN);
    const int key = nt * BN + rowS;
    cscP[rowS] = (pmask[(size_t)b * LK + key] ? 1.0f : 0.0f) /
                 fmaxf(sqrtf(ssqP), EPSN);
    cscN[rowS] = (nmask[(size_t)b * LK + key] ? 1.0f : 0.0f) /
                 fmaxf(sqrtf(ssqN), EPSN);
  }
  __syncthreads();

  float vmp[2][4], vmn[2][4];
  #pragma unroll
  for (int m = 0; m < 2; ++m)
    #pragma unroll
    for (int r = 0; r < 4; ++r) { vmp[m][r] = -INFINITY; vmn[m][r] = -INFINITY; }
  #pragma unroll
  for (int n = 0; n < 4; ++n) {
    const int col = wc * 64 + n * 16 + frow;
    const float sp = cscP[col];
    const float sn = cscN[col];
    #pragma unroll
    for (int m = 0; m < 2; ++m)
      #pragma unroll
      for (int r = 0; r < 4; ++r) {
        vmp[m][r] = fmaxf(vmp[m][r], accp[m][n][r] * sp);
        vmn[m][r] = fmaxf(vmn[m][r], accn[m][n][r] * sn);
      }
  }
  #pragma unroll
  for (int off = 1; off < 16; off <<= 1)
    #pragma unroll
    for (int m = 0; m < 2; ++m)
      #pragma unroll
      for (int r = 0; r < 4; ++r) {
        vmp[m][r] = fmaxf(vmp[m][r], __shfl_xor(vmp[m][r], off));
        vmn[m][r] = fmaxf(vmn[m][r], __shfl_xor(vmn[m][r], off));
      }
  if ((lane & 15) == 0) {
    #pragma unroll
    for (int m = 0; m < 2; ++m)
      #pragma unroll
      for (int r = 0; r < 4; ++r) {
        const int row = wr * 32 + m * 16 + kgrp * 4 + r;
        rmaxP[row * 2 + wc] = vmp[m][r];
        rmaxN[row * 2 + wc] = vmn[m][r];
      }
  }
  __syncthreads();
  if (tid < BM) {
    const float ia = invA_s[tid];
    const float vP = fmaxf(rmaxP[tid * 2], rmaxP[tid * 2 + 1]) * ia;
    const float vN = fmaxf(rmaxN[tid * 2], rmaxN[tid * 2 + 1]) * ia;
    part[(((size_t)0 * NB + b) * 4 + nt) * LQ + mt * BM + tid] = vP;
    part[(((size_t)1 * NB + b) * 4 + nt) * LQ + mt * BM + tid] = vN;
  }
}

// ---------------- logits + softplus per batch (r14-verified) ----------------
__global__ __launch_bounds__(256) void logits_kernel(
    const float* __restrict__ part, const int* __restrict__ qmask,
    float* __restrict__ nll) {
  int b = blockIdx.x;
  int t = threadIdx.x;  // = lq
  float mp = -INFINITY, mn = -INFINITY;
  #pragma unroll
  for (int ntile = 0; ntile < 4; ++ntile) {
    mp = fmaxf(mp, part[(((size_t)0 * NB + b) * 4 + ntile) * LQ + t]);
    mn = fmaxf(mn, part[(((size_t)1 * NB + b) * 4 + ntile) * LQ + t]);
  }
  float qm = qmask[(size_t)b * LQ + t] ? 1.0f : 0.0f;
  float p = mp * qm;  // 1/|q| already folded into part
  float n = mn * qm;
  #pragma unroll
  for (int o = 32; o; o >>= 1) { p += __shfl_down(p, o); n += __shfl_down(n, o); }
  __shared__ float sp[4], sn[4];
  int lane = t & 63, w = t >> 6;
  if (lane == 0) { sp[w] = p; sn[w] = n; }
  __syncthreads();
  if (t == 0) {
    float ps = sp[0] + sp[1] + sp[2] + sp[3];
    float ns = sn[0] + sn[1] + sn[2] + sn[3];
    float z = (ns - ps) * TEMP_INV;
    nll[b] = z > 0.0f ? z + log1pf(expf(-z)) : log1pf(expf(z));
  }
}

__global__ void finalize_kernel(const float* __restrict__ nll, float* __restrict__ out) {
  __shared__ float s[128];
  int t = threadIdx.x;
  s[t] = nll[t];
  __syncthreads();
  #pragma unroll
  for (int o = 64; o; o >>= 1) {
    if (t < o) s[t] += s[t + o];
    __syncthreads();
  }
  if (t == 0) out[0] = s[0] * (1.0f / 128.0f);
}

extern "C" void kernel_launch(void* const* d_in, const int* in_sizes, int n_in,
                              void* d_out, int out_size, void* d_ws, size_t ws_size,
                              hipStream_t stream) {
  const float* q = (const float*)d_in[0];
  const float* pk = (const float*)d_in[1];
  const float* nk = (const float*)d_in[2];
  const int* qm = (const int*)d_in[3];
  const int* pm = (const int*)d_in[4];
  const int* nm = (const int*)d_in[5];

  float* ws = (float*)d_ws;
  float* part = ws;                // 262144 floats: [kt][b][nt][lq]
  float* nll = part + 262144;      // 128 floats

  maxsim_kernel<<<1024, 512, 0, stream>>>(q, pk, nk, pm, nm, part);
  logits_kernel<<<NB, 256, 0, stream>>>(part, qm, nll);
  finalize_kernel<<<1, 128, 0, stream>>>(nll, (float*)d_out);
}